// Round 9
// baseline (240.301 us; speedup 1.0000x reference)
//
#include <hip/hip_runtime.h>
#include <cstdint>
#include <cstddef>

typedef short s16x8 __attribute__((ext_vector_type(8)));
typedef float f32x4 __attribute__((ext_vector_type(4)));

#define MFMA16(a, b, c) __builtin_amdgcn_mfma_f32_16x16x32_bf16((a), (b), (c), 0, 0, 0)

constexpr int LDP = 72;   // stride for 64-col tiles (bf16): staging conflict-free, frag reads 2-way
constexpr int LDW = 136;  // stride for 128-col tiles (bf16): same properties

__device__ __forceinline__ short f2bf(float f) {
    unsigned u = __builtin_bit_cast(unsigned, f);
    u += 0x7FFFu + ((u >> 16) & 1u);   // RNE
    return (short)(u >> 16);
}
__device__ __forceinline__ float bf2f(short s) {
    unsigned u = ((unsigned)(unsigned short)s) << 16;
    return __builtin_bit_cast(float, u);
}
__device__ __forceinline__ unsigned pack2(float a, float b) {
    return (unsigned)(unsigned short)f2bf(a) | ((unsigned)(unsigned short)f2bf(b) << 16);
}
// truncating pack (P >= 0: bias <= 1 bf16 ulp) — saves VALU in hot loop
__device__ __forceinline__ unsigned pack2t(float a, float b) {
    unsigned ua = __builtin_bit_cast(unsigned, a);
    unsigned ub = __builtin_bit_cast(unsigned, b);
    return (ua >> 16) | (ub & 0xFFFF0000u);
}

// async 16B/lane global->LDS copy (global_load_lds_dwordx4). LDS dest is
// wave-uniform base + lane*16 — forces UNPADDED tiles, so only used in the
// GEMMs (qkv/oproj) where the m97 read pattern tolerates the conflicts.
__device__ __forceinline__ void async_ld16(const void* g, void* l) {
    __builtin_amdgcn_global_load_lds(
        (const __attribute__((address_space(1))) unsigned int*)g,
        (__attribute__((address_space(3))) unsigned int*)l, 16, 0, 0);
}

// ---------------------------------------------------------------------------
// Kernel 0: fp32 -> bf16 convert of x and all four weights (once per call).
// ---------------------------------------------------------------------------
__global__ __launch_bounds__(256) void convert_kernel(
    const float* __restrict__ x, const float* __restrict__ Wq,
    const float* __restrict__ Wk, const float* __restrict__ Wv,
    const float* __restrict__ Wo, short* __restrict__ xb, short* __restrict__ wb) {
    const size_t f = ((size_t)blockIdx.x * 256 + threadIdx.x) * 8;   // 8 floats/thread
    const float* src;
    short* dst;
    if (f < 4194304) { src = x + f; dst = xb + f; }
    else {
        size_t wo = f - 4194304;
        int seg = (int)(wo >> 20);
        const float* ws4[4] = {Wq, Wk, Wv, Wo};
        src = ws4[seg] + (wo & 1048575u);
        dst = wb + wo;
    }
    float4 a = ((const float4*)src)[0];
    float4 b = ((const float4*)src)[1];
    *(uint4*)dst = make_uint4(pack2(a.x, a.y), pack2(a.z, a.w),
                              pack2(b.x, b.y), pack2(b.z, b.w));
}

// ---------------------------------------------------------------------------
// Kernel 1: QKV projection, m97-structure (128x128 tile, BK=64, async stage).
// R16 XCD-chunked swizzle kept (FETCH evidence shows locality works).
// Q,K -> [B,H,T,D] bf16 (unrotated); V -> [B,H,D,T] bf16 (pre-transposed).
// ---------------------------------------------------------------------------
__global__ __launch_bounds__(256) void qkv_kernel(
    const short* __restrict__ xb, const short* __restrict__ wb,
    short* __restrict__ Qo, short* __restrict__ Ko, short* __restrict__ VTo) {
    __shared__ __align__(16) short sA[128 * 64];
    __shared__ __align__(16) short sB[128 * 64];
    const int tid = threadIdx.x;
    const int w = tid >> 6, lane = tid & 63, quad = lane >> 4, l15 = lane & 15;
    const int wm = w & 1, wn = w >> 1;
    // XCD swizzle: wid 0..767; xcd = wid&7; i = wid>>3 (0..95)
    const int wid = blockIdx.x + blockIdx.y * 24;
    const int xcd = wid & 7, si = wid >> 3;
    const int bx = (xcd & 1) * 12 + si % 12;
    const int by = (xcd >> 1) * 8 + si / 12;
    const int m0 = by * 128;
    const int nb = bx * 128;

    f32x4 acc[4][4];
#pragma unroll
    for (int i = 0; i < 4; i++)
#pragma unroll
        for (int j = 0; j < 4; j++) acc[i][j] = f32x4{0.f, 0.f, 0.f, 0.f};

    for (int kb = 0; kb < 16; kb++) {
        const int k0 = kb * 64;
        if (kb) __syncthreads();
#pragma unroll
        for (int i = 0; i < 4; i++) {
            int c = i * 256 + tid;             // 16B chunk id
            int row = c >> 3, col8 = (c & 7) * 8;
            async_ld16(xb + (size_t)(m0 + row) * 1024 + k0 + col8,
                       &sA[(i * 256 + w * 64) * 8]);
            async_ld16(wb + (size_t)(nb + row) * 1024 + k0 + col8,
                       &sB[(i * 256 + w * 64) * 8]);
        }
        __syncthreads();
#pragma unroll
        for (int ks = 0; ks < 2; ks++) {
            s16x8 av[4], bv[4];
#pragma unroll
            for (int at = 0; at < 4; at++)
                av[at] = *(const s16x8*)&sA[(wm * 64 + at * 16 + l15) * 64 + ks * 32 + quad * 8];
#pragma unroll
            for (int bt = 0; bt < 4; bt++)
                bv[bt] = *(const s16x8*)&sB[(wn * 64 + bt * 16 + l15) * 64 + ks * 32 + quad * 8];
#pragma unroll
            for (int at = 0; at < 4; at++)
#pragma unroll
                for (int bt = 0; bt < 4; bt++)
                    acc[at][bt] = MFMA16(av[at], bv[bt], acc[at][bt]);
        }
    }

    const int wsel = bx >> 3;                 // 0=q 1=k 2=v
    const int h = (bx & 7) * 2 + wn;          // head (uniform per wave)
    if (wsel == 2) {
#pragma unroll
        for (int at = 0; at < 4; at++) {
            int m = m0 + wm * 64 + at * 16 + quad * 4;
            int b = m >> 11, t0 = m & 2047;
            size_t base = ((size_t)((b * 16 + h) * 64)) * 2048;
#pragma unroll
            for (int bt = 0; bt < 4; bt++) {
                int d = bt * 16 + l15;
                unsigned lo = pack2(acc[at][bt][0], acc[at][bt][1]);
                unsigned hi = pack2(acc[at][bt][2], acc[at][bt][3]);
                *(uint2*)&VTo[base + (size_t)d * 2048 + t0] = make_uint2(lo, hi);
            }
        }
    } else {
        short* Out = (wsel == 0) ? Qo : Ko;
#pragma unroll
        for (int at = 0; at < 4; at++)
#pragma unroll
            for (int r = 0; r < 4; r++) {
                int m = m0 + wm * 64 + at * 16 + quad * 4 + r;
                int b = m >> 11, t = m & 2047;
                size_t base = (((size_t)(b * 16 + h)) * 2048 + t) * 64;
#pragma unroll
                for (int bt = 0; bt < 4; bt++)
                    Out[base + bt * 16 + l15] = f2bf(acc[at][bt][r]);
            }
    }
}

// ---------------------------------------------------------------------------
// Kernel 2: RoPE in-place on Q and K. Q pre-scaled by 0.125*log2(e) (exp2
// domain softmax). Native v_sin/v_cos (revolutions).
// ---------------------------------------------------------------------------
__global__ __launch_bounds__(256) void rope_kernel(short* __restrict__ Q, short* __restrict__ K) {
    const int rid = blockIdx.x * 256 + threadIdx.x;   // 0..131071
    const bool isK = (rid & 65536) != 0;
    short* buf = isK ? K : Q;
    const float sc = isK ? 1.0f : 0.18033688011112042f;   // 1/8 * log2(e)
    const int r2 = rid & 65535;          // bh*2048 + t
    const int t = r2 & 2047;
    short* row = buf + (size_t)r2 * 64;

    unsigned wv[32];
    const uint4* rp = (const uint4*)row;
#pragma unroll
    for (int c = 0; c < 8; c++) {
        uint4 v = rp[c];
        wv[c * 4 + 0] = v.x; wv[c * 4 + 1] = v.y; wv[c * 4 + 2] = v.z; wv[c * 4 + 3] = v.w;
    }
    float y1[32], y2[32];
    const float tf = (float)t;
#pragma unroll
    for (int i = 0; i < 32; i++) {
        float x1 = bf2f((short)(wv[i] & 0xFFFFu));
        float x2 = bf2f((short)(wv[i] >> 16));
        float inv = exp2f((float)i * -0.4152410118609203f);  // 10000^(-i/32), const-folded
        float rev = tf * inv * 0.15915494309189535f;         // fr / 2pi
        rev = rev - floorf(rev);
        float sn = __builtin_amdgcn_sinf(rev);               // sin(rev*2pi) = sin(fr)
        float cs = __builtin_amdgcn_cosf(rev);
        y1[i] = (x1 * cs - x2 * sn) * sc;
        y2[i] = (x1 * sn + x2 * cs) * sc;
    }
    unsigned ow[32];
#pragma unroll
    for (int i = 0; i < 16; i++) ow[i] = pack2(y1[2 * i], y1[2 * i + 1]);
#pragma unroll
    for (int i = 0; i < 16; i++) ow[16 + i] = pack2(y2[2 * i], y2[2 * i + 1]);
    uint4* wp = (uint4*)row;
#pragma unroll
    for (int c = 0; c < 8; c++)
        wp[c] = make_uint4(ow[c * 4 + 0], ow[c * 4 + 1], ow[c * 4 + 2], ow[c * 4 + 3]);
}

// ---------------------------------------------------------------------------
// Kernel 3: causal flash attention — R18: single launch (R17 split reverted:
// +8.7us for nothing) = R7 base (XCD swizzle, 48.4us) + V DIRECT FROM GLOBAL
// (R5 retry WITHOUT launch_bounds — R5's failure was the (256,4) hint forcing
// the 64-VGPR tier and spilling; the idea itself was never measured).
// sVT eliminated: V MFMA B-frags are per-lane 16B loads from V^T (64B-granule
// coalesced, XCD-local L2 hits post-swizzle). Banked issue: ks2=0,1 after the
// staging barrier (covered by QK^T+softmax); ks2=2 after P-writes; ks2=3
// after PV step 0. LDS 53248 -> 35840 (4 blocks/CU); K staging halves the
// serial drain. Failure check: VGPR must be ~100-128, WRITE ~21MB (64 VGPR +
// WRITE spike = spill trap -> abandon V-direct).
// ---------------------------------------------------------------------------
__global__ __launch_bounds__(256) void attn_kernel(
    const short* __restrict__ Q, const short* __restrict__ K,
    const short* __restrict__ VT, short* __restrict__ paO, float* __restrict__ ml) {
    __shared__ __align__(16) short sQP[64 * LDW];   // P (64q x 128k)
    __shared__ __align__(16) short sK[128 * LDP];   // 128 keys x 64 d

    const int tid = threadIdx.x;
    const int w = tid >> 6, lane = tid & 63, quad = lane >> 4, l15 = lane & 15;
    // XCD swizzle: wid 0..2559; xcd = wid&7 (HW round-robin); si = wid>>3.
    const int wid = blockIdx.x + blockIdx.y * 80;
    const int xcd = wid & 7, si = wid >> 3;
    const int bh = xcd * 4 + si / 80;
    const int u = 79 - (si % 80);

    int qt, c;
    if (u < 8)       { qt = u; c = 0; }
    else if (u < 24) { int v = u - 8;  qt = 8 + (v >> 1); c = v & 1; }
    else if (u < 48) { int v = u - 24; qt = 16 + v / 3;   c = v - 3 * (qt - 16); }
    else             { int v = u - 48; qt = 24 + (v >> 2); c = v & 3; }
    const int kbDiag = qt >> 1;              // 128-key block containing the diagonal
    const int kb0 = c * 4;
    const int kb1 = min(kb0 + 3, kbDiag);

    const short* Qp = Q + (size_t)bh * 2048 * 64;
    const short* Kp = K + (size_t)bh * 2048 * 64;
    const short* Vp = VT + (size_t)bh * 64 * 2048;   // [d][t]

    // K staging geometry: chunk p = tid + i*256 -> row=(tid>>3)+i*32, col8=(tid&7)*8
    const int krow = tid >> 3, kcol = (tid & 7) * 8;
    const short* Kld = Kp + (size_t)krow * 64 + kcol;     // + kb*8192 + i*2048
    short* sKw = &sK[krow * LDP + kcol];

    // Named prefetch registers — NOT arrays, NOT lambda-captured (R10 lesson).
    uint4 kr0, kr1, kr2, kr3;
#define LOADK(KB) do {                                                   \
        const short* _kp = Kld + (size_t)(KB) * 8192;                    \
        kr0 = *(const uint4*)(_kp);                                      \
        kr1 = *(const uint4*)(_kp + 32 * 64);                            \
        kr2 = *(const uint4*)(_kp + 64 * 64);                            \
        kr3 = *(const uint4*)(_kp + 96 * 64);                            \
    } while (0)

    // V fragment: lane reads V^T[d = ct*16+l15][key = kb*128 + ks2*32 + quad*8]
    const short* Vf = Vp + (size_t)l15 * 2048 + quad * 8;
#define VFRAG(CT, KB, KS2) \
    (*(const s16x8*)(Vf + (size_t)(CT) * 32768 + (KB) * 128 + (KS2) * 32))

    // Q fragment DIRECT to registers (wave reads only its own 16 q-rows).
    s16x8 aq[2];
#pragma unroll
    for (int ks = 0; ks < 2; ks++)
        aq[ks] = *(const s16x8*)(Qp + (size_t)(qt * 64 + w * 16 + l15) * 64 + ks * 32 + quad * 8);
    LOADK(kb0);                      // prologue K prefetch

    f32x4 o[4];
#pragma unroll
    for (int i = 0; i < 4; i++) o[i] = f32x4{0.f, 0.f, 0.f, 0.f};
    float lrun = 0.f;                // per-lane partial sum (quad-reduced at end)
    const int q_idx = qt * 64 + w * 16 + l15;

    for (int kb = kb0; kb <= kb1; kb++) {
        __syncthreads();             // prior iter's sK/sQP readers done
        // drain prefetched K regs -> LDS (loads issued one compute-phase ago)
        *(uint4*)(sKw)            = kr0;
        *(uint4*)(sKw + 32 * LDP) = kr1;
        *(uint4*)(sKw + 64 * LDP) = kr2;
        *(uint4*)(sKw + 96 * LDP) = kr3;
        __syncthreads();
        if (kb < kb1) LOADK(kb + 1);    // issue next K tile; lands during compute

        // V banks for ks2=0,1 — issued here, land under QK^T + softmax
        s16x8 va0 = VFRAG(0, kb, 0), va1 = VFRAG(1, kb, 0),
              va2 = VFRAG(2, kb, 0), va3 = VFRAG(3, kb, 0);
        s16x8 vb0 = VFRAG(0, kb, 1), vb1 = VFRAG(1, kb, 1),
              vb2 = VFRAG(2, kb, 1), vb3 = VFRAG(3, kb, 1);

        // S^T: 128 keys x 16 queries per wave. A = K rows (keys), B = Q^T.
        f32x4 sa[8];
#pragma unroll
        for (int i = 0; i < 8; i++) sa[i] = f32x4{0.f, 0.f, 0.f, 0.f};
        __builtin_amdgcn_s_setprio(1);
#pragma unroll
        for (int ks = 0; ks < 2; ks++) {
#pragma unroll
            for (int ct = 0; ct < 8; ct++) {
                s16x8 kf = *(const s16x8*)&sK[(ct * 16 + l15) * LDP + ks * 32 + quad * 8];
                sa[ct] = MFMA16(kf, aq[ks], sa[ct]);
            }
        }
        __builtin_amdgcn_s_setprio(0);

        float ps[8][4];
#pragma unroll
        for (int ct = 0; ct < 8; ct++)
#pragma unroll
            for (int r = 0; r < 4; r++) ps[ct][r] = sa[ct][r];

        if (kb == kbDiag) {          // uniform branch: only the diagonal block masks
#pragma unroll
            for (int ct = 0; ct < 8; ct++) {
                int kbase = kb * 128 + ct * 16 + quad * 4;
#pragma unroll
                for (int r = 0; r < 4; r++)
                    if ((kbase + r) > q_idx) ps[ct][r] = -INFINITY;
            }
        }

        // P = exp2(s) (no max subtraction), accumulate per-lane l
        float cm[8];
#pragma unroll
        for (int ct = 0; ct < 8; ct++) {
#pragma unroll
            for (int r = 0; r < 4; r++) ps[ct][r] = __builtin_amdgcn_exp2f(ps[ct][r]);
            cm[ct] = (ps[ct][0] + ps[ct][1]) + (ps[ct][2] + ps[ct][3]);
        }
        lrun += ((cm[0] + cm[1]) + (cm[2] + cm[3])) + ((cm[4] + cm[5]) + (cm[6] + cm[7]));

        // P^T (C-layout) -> sQP rows = query (wave-private), 8x ds_write_b64
#pragma unroll
        for (int ct = 0; ct < 8; ct++) {
            unsigned lo = pack2t(ps[ct][0], ps[ct][1]);
            unsigned hi = pack2t(ps[ct][2], ps[ct][3]);
            *(uint2*)&sQP[(w * 16 + l15) * LDW + ct * 16 + quad * 4] = make_uint2(lo, hi);
        }
        // no barrier: rows are wave-private, same-wave DS ops in-order

        // V bank for ks2=2 — lands under PV steps 0-1
        s16x8 vc0 = VFRAG(0, kb, 2), vc1 = VFRAG(1, kb, 2),
              vc2 = VFRAG(2, kb, 2), vc3 = VFRAG(3, kb, 2);

        // O += P V — banked V, loads interleaved with MFMA clusters.
        __builtin_amdgcn_s_setprio(1);
        {
            s16x8 pa;
            // step 0: consume bank A (ks2=0)
            pa = *(const s16x8*)&sQP[(w * 16 + l15) * LDW + 0 * 32 + quad * 8];
            o[0] = MFMA16(pa, va0, o[0]); o[1] = MFMA16(pa, va1, o[1]);
            o[2] = MFMA16(pa, va2, o[2]); o[3] = MFMA16(pa, va3, o[3]);
            // V bank for ks2=3 — lands under PV steps 1-2
            s16x8 vd0 = VFRAG(0, kb, 3), vd1 = VFRAG(1, kb, 3),
                  vd2 = VFRAG(2, kb, 3), vd3 = VFRAG(3, kb, 3);
            // step 1: consume bank B (ks2=1)
            pa = *(const s16x8*)&sQP[(w * 16 + l15) * LDW + 1 * 32 + quad * 8];
            o[0] = MFMA16(pa, vb0, o[0]); o[1] = MFMA16(pa, vb1, o[1]);
            o[2] = MFMA16(pa, vb2, o[2]); o[3] = MFMA16(pa, vb3, o[3]);
            // step 2: consume bank C (ks2=2)
            pa = *(const s16x8*)&sQP[(w * 16 + l15) * LDW + 2 * 32 + quad * 8];
            o[0] = MFMA16(pa, vc0, o[0]); o[1] = MFMA16(pa, vc1, o[1]);
            o[2] = MFMA16(pa, vc2, o[2]); o[3] = MFMA16(pa, vc3, o[3]);
            // step 3: consume bank D (ks2=3)
            pa = *(const s16x8*)&sQP[(w * 16 + l15) * LDW + 3 * 32 + quad * 8];
            o[0] = MFMA16(pa, vd0, o[0]); o[1] = MFMA16(pa, vd1, o[1]);
            o[2] = MFMA16(pa, vd2, o[2]); o[3] = MFMA16(pa, vd3, o[3]);
        }
        __builtin_amdgcn_s_setprio(0);
    }
#undef LOADK
#undef VFRAG

    // epilogue: UNNORMALIZED partial O (bf16) + l (fp32, per query)
    const size_t pbase = ((size_t)(bh * 80 + u)) * 4096;
#pragma unroll
    for (int r = 0; r < 4; r++) {
        int row = w * 16 + quad * 4 + r;
#pragma unroll
        for (int ct = 0; ct < 4; ct++)
            paO[pbase + row * 64 + ct * 16 + l15] = f2bf(o[ct][r]);
    }
    lrun += __shfl_xor(lrun, 16);
    lrun += __shfl_xor(lrun, 32);
    if (quad == 0)
        ml[(bh * 80 + u) * 64 + w * 16 + l15] = lrun;
}

// ---------------------------------------------------------------------------
// Kernel 3b: combine partials (no-max scheme: L = sum l_i, Y = sum O_i / L).
// ---------------------------------------------------------------------------
__global__ __launch_bounds__(256) void combine_kernel(
    const short* __restrict__ paO, const float* __restrict__ ml, short* __restrict__ Y) {
    const int qt = blockIdx.x, bh = blockIdx.y;
    const int b = bh >> 4, h = bh & 15;
    const int nch = (qt >> 3) + 1;
    int base;
    if (qt < 8) base = qt;
    else if (qt < 16) base = 8 + 2 * (qt - 8);
    else if (qt < 24) base = 24 + 3 * (qt - 16);
    else base = 48 + 4 * (qt - 24);

    const int row = threadIdx.x >> 2;
    const int cq = (threadIdx.x & 3) * 16;

    float L = 0.f;
    for (int i = 0; i < nch; i++)
        L += ml[(bh * 80 + base + i) * 64 + row];
    const float inv = 1.0f / L;

    float acc[16];
#pragma unroll
    for (int j = 0; j < 16; j++) acc[j] = 0.f;
    for (int i = 0; i < nch; i++) {
        const short* p = paO + ((size_t)(bh * 80 + base + i)) * 4096 + row * 64 + cq;
        uint4 v0 = ((const uint4*)p)[0];
        uint4 v1 = ((const uint4*)p)[1];
        unsigned vs[8] = {v0.x, v0.y, v0.z, v0.w, v1.x, v1.y, v1.z, v1.w};
#pragma unroll
        for (int j = 0; j < 8; j++) {
            acc[2 * j + 0] += bf2f((short)(vs[j] & 0xFFFFu));
            acc[2 * j + 1] += bf2f((short)(vs[j] >> 16));
        }
    }
    const int t = qt * 64 + row;
    short* yp = Y + ((size_t)(b * 2048 + t)) * 1024 + h * 64 + cq;
    unsigned ow[8];
#pragma unroll
    for (int j = 0; j < 8; j++) ow[j] = pack2(acc[2 * j] * inv, acc[2 * j + 1] * inv);
    ((uint4*)yp)[0] = make_uint4(ow[0], ow[1], ow[2], ow[3]);
    ((uint4*)yp)[1] = make_uint4(ow[4], ow[5], ow[6], ow[7]);
}

// ---------------------------------------------------------------------------
// Kernel 4: output projection, 64x128 tiles -> 512 blocks. R16 XCD swizzle
// kept. Wave w owns a 64x32 slab. fp32 out.
// ---------------------------------------------------------------------------
__global__ __launch_bounds__(256) void oproj_kernel(
    const short* __restrict__ Yb, const short* __restrict__ Wob, float* __restrict__ out) {
    __shared__ __align__(16) short sA[64 * 64];
    __shared__ __align__(16) short sB[128 * 64];
    const int tid = threadIdx.x;
    const int w = tid >> 6, lane = tid & 63, quad = lane >> 4, l15 = lane & 15;
    // XCD swizzle: wid 0..511; xcd = wid&7; i = wid>>3 (0..63)
    const int wid = blockIdx.x + blockIdx.y * 8;
    const int xcd = wid & 7, si = wid >> 3;
    const int m0 = (xcd * 8 + (si >> 3)) * 64;
    const int nb = (si & 7) * 128;

    f32x4 acc[4][2];
#pragma unroll
    for (int i = 0; i < 4; i++)
#pragma unroll
        for (int j = 0; j < 2; j++) acc[i][j] = f32x4{0.f, 0.f, 0.f, 0.f};

    for (int kb = 0; kb < 16; kb++) {
        const int k0 = kb * 64;
        if (kb) __syncthreads();
#pragma unroll
        for (int i = 0; i < 2; i++) {      // A: 64x64 shorts = 512 chunks
            int c = i * 256 + tid;
            int row = c >> 3, col8 = (c & 7) * 8;
            async_ld16(Yb + (size_t)(m0 + row) * 1024 + k0 + col8,
                       &sA[(i * 256 + w * 64) * 8]);
        }
#pragma unroll
        for (int i = 0; i < 4; i++) {      // B: 128x64 shorts = 1024 chunks
            int c = i * 256 + tid;
            int row = c >> 3, col8 = (c & 7) * 8;
            async_ld16(Wob + (size_t)(nb + row) * 1024 + k0 + col8,
                       &sB[(i * 256 + w * 64) * 8]);
        }
        __syncthreads();
#pragma unroll
        for (int ks = 0; ks < 2; ks++) {
            s16x8 av[4], bv[2];
#pragma unroll
            for (int at = 0; at < 4; at++)
                av[at] = *(const s16x8*)&sA[(at * 16 + l15) * 64 + ks * 32 + quad * 8];
#pragma unroll
            for (int bt = 0; bt < 2; bt++)
                bv[bt] = *(const s16x8*)&sB[(w * 32 + bt * 16 + l15) * 64 + ks * 32 + quad * 8];
#pragma unroll
            for (int at = 0; at < 4; at++)
#pragma unroll
                for (int bt = 0; bt < 2; bt++)
                    acc[at][bt] = MFMA16(av[at], bv[bt], acc[at][bt]);
        }
    }
#pragma unroll
    for (int at = 0; at < 4; at++)
#pragma unroll
        for (int r = 0; r < 4; r++) {
            int m = m0 + at * 16 + quad * 4 + r;
#pragma unroll
            for (int bt = 0; bt < 2; bt++) {
                int n = nb + w * 32 + bt * 16 + l15;
                out[(size_t)m * 1024 + n] = acc[at][bt][r];
            }
        }
}

extern "C" void kernel_launch(void* const* d_in, const int* in_sizes, int n_in,
                              void* d_out, int out_size, void* d_ws, size_t ws_size,
                              hipStream_t stream) {
    (void)in_sizes; (void)n_in; (void)out_size; (void)ws_size;
    const float* x  = (const float*)d_in[0];
    const float* Wq = (const float*)d_in[1];
    const float* Wk = (const float*)d_in[2];
    const float* Wv = (const float*)d_in[3];
    const float* Wo = (const float*)d_in[4];
    float* out = (float*)d_out;

    const size_t NE = (size_t)2 * 16 * 2048 * 64;   // 4M elems per tensor
    short* Q   = (short*)d_ws;
    short* K   = Q + NE;
    short* VT  = K + NE;          // [B,H,D,T]
    short* Y   = VT + NE;         // attn output [B,T,C] bf16
    short* xb  = Y;               // x bf16 ALIASES Y: consumed by qkv before combine writes Y
    short* wb  = Y + NE;          // [Wq|Wk|Wv|Wo] bf16, 4M elems
    short* paO = wb + NE;         // partial O: 32 bh x 80 units x 64x64 bf16 = 21 MB
    float* ml  = (float*)(paO + (size_t)32 * 80 * 4096);   // l: 32x80x64 fp32

    convert_kernel<<<4096, 256, 0, stream>>>(x, Wq, Wk, Wv, Wo, xb, wb);
    qkv_kernel<<<dim3(24, 32), 256, 0, stream>>>(xb, wb, Q, K, VT);
    rope_kernel<<<512, 256, 0, stream>>>(Q, K);
    attn_kernel<<<dim3(80, 32), 256, 0, stream>>>(Q, K, VT, paO, ml);
    combine_kernel<<<dim3(32, 32), 256, 0, stream>>>(paO, ml, Y);
    oproj_kernel<<<dim3(8, 64), 256, 0, stream>>>(Y, wb + 3 * 1048576, out);
}

// Round 10
// 196.140 us; speedup vs baseline: 1.2252x; 1.2252x over previous
//
#include <hip/hip_runtime.h>
#include <cstdint>
#include <cstddef>

typedef short s16x8 __attribute__((ext_vector_type(8)));
typedef float f32x4 __attribute__((ext_vector_type(4)));

#define MFMA16(a, b, c) __builtin_amdgcn_mfma_f32_16x16x32_bf16((a), (b), (c), 0, 0, 0)

constexpr int LDP = 72;   // stride for 64-col tiles (bf16): staging conflict-free, frag reads 2-way
constexpr int LDW = 136;  // stride for 128-col tiles (bf16): same properties

__device__ __forceinline__ short f2bf(float f) {
    unsigned u = __builtin_bit_cast(unsigned, f);
    u += 0x7FFFu + ((u >> 16) & 1u);   // RNE
    return (short)(u >> 16);
}
__device__ __forceinline__ float bf2f(short s) {
    unsigned u = ((unsigned)(unsigned short)s) << 16;
    return __builtin_bit_cast(float, u);
}
__device__ __forceinline__ unsigned pack2(float a, float b) {
    return (unsigned)(unsigned short)f2bf(a) | ((unsigned)(unsigned short)f2bf(b) << 16);
}
// truncating pack (P >= 0: bias <= 1 bf16 ulp) — saves VALU in hot loop
__device__ __forceinline__ unsigned pack2t(float a, float b) {
    unsigned ua = __builtin_bit_cast(unsigned, a);
    unsigned ub = __builtin_bit_cast(unsigned, b);
    return (ua >> 16) | (ub & 0xFFFF0000u);
}

// async 16B/lane global->LDS copy (global_load_lds_dwordx4). LDS dest is
// wave-uniform base + lane*16 — forces UNPADDED tiles, so only used in the
// GEMMs (qkv/oproj) where the m97 read pattern tolerates the conflicts.
// R9 lesson: using it in attn cost ~29us of bank-conflict serialization.
__device__ __forceinline__ void async_ld16(const void* g, void* l) {
    __builtin_amdgcn_global_load_lds(
        (const __attribute__((address_space(1))) unsigned int*)g,
        (__attribute__((address_space(3))) unsigned int*)l, 16, 0, 0);
}

// ---------------------------------------------------------------------------
// Kernel 0: fp32 -> bf16 convert of x and all four weights (once per call).
// ---------------------------------------------------------------------------
__global__ __launch_bounds__(256) void convert_kernel(
    const float* __restrict__ x, const float* __restrict__ Wq,
    const float* __restrict__ Wk, const float* __restrict__ Wv,
    const float* __restrict__ Wo, short* __restrict__ xb, short* __restrict__ wb) {
    const size_t f = ((size_t)blockIdx.x * 256 + threadIdx.x) * 8;   // 8 floats/thread
    const float* src;
    short* dst;
    if (f < 4194304) { src = x + f; dst = xb + f; }
    else {
        size_t wo = f - 4194304;
        int seg = (int)(wo >> 20);
        const float* ws4[4] = {Wq, Wk, Wv, Wo};
        src = ws4[seg] + (wo & 1048575u);
        dst = wb + wo;
    }
    float4 a = ((const float4*)src)[0];
    float4 b = ((const float4*)src)[1];
    *(uint4*)dst = make_uint4(pack2(a.x, a.y), pack2(a.z, a.w),
                              pack2(b.x, b.y), pack2(b.z, b.w));
}

// ---------------------------------------------------------------------------
// Kernel 1: QKV projection, m97-structure (128x128 tile, BK=64, async stage).
// R16: XCD-chunked swizzle — HW round-robins wgid%8 across XCDs, so decode
// (xcd, i) from wgid and give each XCD a 12x8 (bx,by) sub-grid: per-XCD L2
// working set 12 B-panels (3MB) + 8 A-panels (2MB) ~ 5MB vs 14MB default.
// Q,K -> [B,H,T,D] bf16 (unrotated); V -> [B,H,D,T] bf16 (pre-transposed).
// ---------------------------------------------------------------------------
__global__ __launch_bounds__(256) void qkv_kernel(
    const short* __restrict__ xb, const short* __restrict__ wb,
    short* __restrict__ Qo, short* __restrict__ Ko, short* __restrict__ VTo) {
    __shared__ __align__(16) short sA[128 * 64];
    __shared__ __align__(16) short sB[128 * 64];
    const int tid = threadIdx.x;
    const int w = tid >> 6, lane = tid & 63, quad = lane >> 4, l15 = lane & 15;
    const int wm = w & 1, wn = w >> 1;
    // XCD swizzle: wid 0..767; xcd = wid&7; i = wid>>3 (0..95)
    const int wid = blockIdx.x + blockIdx.y * 24;
    const int xcd = wid & 7, si = wid >> 3;
    const int bx = (xcd & 1) * 12 + si % 12;
    const int by = (xcd >> 1) * 8 + si / 12;
    const int m0 = by * 128;
    const int nb = bx * 128;

    f32x4 acc[4][4];
#pragma unroll
    for (int i = 0; i < 4; i++)
#pragma unroll
        for (int j = 0; j < 4; j++) acc[i][j] = f32x4{0.f, 0.f, 0.f, 0.f};

    for (int kb = 0; kb < 16; kb++) {
        const int k0 = kb * 64;
        if (kb) __syncthreads();
#pragma unroll
        for (int i = 0; i < 4; i++) {
            int c = i * 256 + tid;             // 16B chunk id
            int row = c >> 3, col8 = (c & 7) * 8;
            async_ld16(xb + (size_t)(m0 + row) * 1024 + k0 + col8,
                       &sA[(i * 256 + w * 64) * 8]);
            async_ld16(wb + (size_t)(nb + row) * 1024 + k0 + col8,
                       &sB[(i * 256 + w * 64) * 8]);
        }
        __syncthreads();
#pragma unroll
        for (int ks = 0; ks < 2; ks++) {
            s16x8 av[4], bv[4];
#pragma unroll
            for (int at = 0; at < 4; at++)
                av[at] = *(const s16x8*)&sA[(wm * 64 + at * 16 + l15) * 64 + ks * 32 + quad * 8];
#pragma unroll
            for (int bt = 0; bt < 4; bt++)
                bv[bt] = *(const s16x8*)&sB[(wn * 64 + bt * 16 + l15) * 64 + ks * 32 + quad * 8];
#pragma unroll
            for (int at = 0; at < 4; at++)
#pragma unroll
                for (int bt = 0; bt < 4; bt++)
                    acc[at][bt] = MFMA16(av[at], bv[bt], acc[at][bt]);
        }
    }

    const int wsel = bx >> 3;                 // 0=q 1=k 2=v
    const int h = (bx & 7) * 2 + wn;          // head (uniform per wave)
    if (wsel == 2) {
#pragma unroll
        for (int at = 0; at < 4; at++) {
            int m = m0 + wm * 64 + at * 16 + quad * 4;
            int b = m >> 11, t0 = m & 2047;
            size_t base = ((size_t)((b * 16 + h) * 64)) * 2048;
#pragma unroll
            for (int bt = 0; bt < 4; bt++) {
                int d = bt * 16 + l15;
                unsigned lo = pack2(acc[at][bt][0], acc[at][bt][1]);
                unsigned hi = pack2(acc[at][bt][2], acc[at][bt][3]);
                *(uint2*)&VTo[base + (size_t)d * 2048 + t0] = make_uint2(lo, hi);
            }
        }
    } else {
        short* Out = (wsel == 0) ? Qo : Ko;
#pragma unroll
        for (int at = 0; at < 4; at++)
#pragma unroll
            for (int r = 0; r < 4; r++) {
                int m = m0 + wm * 64 + at * 16 + quad * 4 + r;
                int b = m >> 11, t = m & 2047;
                size_t base = (((size_t)(b * 16 + h)) * 2048 + t) * 64;
#pragma unroll
                for (int bt = 0; bt < 4; bt++)
                    Out[base + bt * 16 + l15] = f2bf(acc[at][bt][r]);
            }
    }
}

// ---------------------------------------------------------------------------
// Kernel 2: RoPE in-place on Q and K. Q pre-scaled by 0.125*log2(e) (exp2
// domain softmax). Native v_sin/v_cos (revolutions).
// ---------------------------------------------------------------------------
__global__ __launch_bounds__(256) void rope_kernel(short* __restrict__ Q, short* __restrict__ K) {
    const int rid = blockIdx.x * 256 + threadIdx.x;   // 0..131071
    const bool isK = (rid & 65536) != 0;
    short* buf = isK ? K : Q;
    const float sc = isK ? 1.0f : 0.18033688011112042f;   // 1/8 * log2(e)
    const int r2 = rid & 65535;          // bh*2048 + t
    const int t = r2 & 2047;
    short* row = buf + (size_t)r2 * 64;

    unsigned wv[32];
    const uint4* rp = (const uint4*)row;
#pragma unroll
    for (int c = 0; c < 8; c++) {
        uint4 v = rp[c];
        wv[c * 4 + 0] = v.x; wv[c * 4 + 1] = v.y; wv[c * 4 + 2] = v.z; wv[c * 4 + 3] = v.w;
    }
    float y1[32], y2[32];
    const float tf = (float)t;
#pragma unroll
    for (int i = 0; i < 32; i++) {
        float x1 = bf2f((short)(wv[i] & 0xFFFFu));
        float x2 = bf2f((short)(wv[i] >> 16));
        float inv = exp2f((float)i * -0.4152410118609203f);  // 10000^(-i/32), const-folded
        float rev = tf * inv * 0.15915494309189535f;         // fr / 2pi
        rev = rev - floorf(rev);
        float sn = __builtin_amdgcn_sinf(rev);               // sin(rev*2pi) = sin(fr)
        float cs = __builtin_amdgcn_cosf(rev);
        y1[i] = (x1 * cs - x2 * sn) * sc;
        y2[i] = (x1 * sn + x2 * cs) * sc;
    }
    unsigned ow[32];
#pragma unroll
    for (int i = 0; i < 16; i++) ow[i] = pack2(y1[2 * i], y1[2 * i + 1]);
#pragma unroll
    for (int i = 0; i < 16; i++) ow[16 + i] = pack2(y2[2 * i], y2[2 * i + 1]);
    uint4* wp = (uint4*)row;
#pragma unroll
    for (int c = 0; c < 8; c++)
        wp[c] = make_uint4(ow[c * 4 + 0], ow[c * 4 + 1], ow[c * 4 + 2], ow[c * 4 + 3]);
}

// ---------------------------------------------------------------------------
// Kernel 3: causal flash attention — R19 = exact R16/R7 config (best measured
// 48.4us, total 196.9us). R4 core + XCD-chunked swizzle: each XCD owns 4 bh
// (K/V working set ~3MB fits its private 4MB L2 — FETCH 59.5->12.3MB proven
// R7). V STAYS IN LDS: V-direct-from-global falsified twice (R5: spill trap;
// R9: clean counters, still +41us — strided V^T frag loads in the PV critical
// path can't match ds_read). Retained: named-reg K/V prefetch (R11, T14),
// Q direct-to-reg (R13), 80-unit/4-chunk map, setprio, exp2 no-max softmax.
// ---------------------------------------------------------------------------
__global__ __launch_bounds__(256) void attn_kernel(
    const short* __restrict__ Q, const short* __restrict__ K,
    const short* __restrict__ VT, short* __restrict__ paO, float* __restrict__ ml) {
    __shared__ __align__(16) short sQP[64 * LDW];   // P (64q x 128k)
    __shared__ __align__(16) short sK[128 * LDP];   // 128 keys x 64 d
    __shared__ __align__(16) short sVT[64 * LDW];   // 64 d x 128 keys

    const int tid = threadIdx.x;
    const int w = tid >> 6, lane = tid & 63, quad = lane >> 4, l15 = lane & 15;
    // XCD swizzle: wid 0..2559; xcd = wid&7 (HW round-robin); si = wid>>3.
    // bh = xcd*4 + si/80 (4 bh per XCD); u = 79-(si%80) (largest-qt first).
    const int wid = blockIdx.x + blockIdx.y * 80;
    const int xcd = wid & 7, si = wid >> 3;
    const int bh = xcd * 4 + si / 80;
    const int u = 79 - (si % 80);

    int qt, c;
    if (u < 8)       { qt = u; c = 0; }
    else if (u < 24) { int v = u - 8;  qt = 8 + (v >> 1); c = v & 1; }
    else if (u < 48) { int v = u - 24; qt = 16 + v / 3;   c = v - 3 * (qt - 16); }
    else             { int v = u - 48; qt = 24 + (v >> 2); c = v & 3; }
    const int kbDiag = qt >> 1;              // 128-key block containing the diagonal
    const int kb0 = c * 4;
    const int kb1 = min(kb0 + 3, kbDiag);

    const short* Qp = Q + (size_t)bh * 2048 * 64;
    const short* Kp = K + (size_t)bh * 2048 * 64;
    const short* Vp = VT + (size_t)bh * 64 * 2048;   // [d][t]

    // Per-thread staging geometry:
    //   K : chunk p = tid + i*256 -> row=(tid>>3)+i*32, col8=(tid&7)*8
    //   VT: chunk p = tid + i*256 -> row=(tid>>4)+i*16, c16=(tid&15)*8
    const int krow = tid >> 3, kcol = (tid & 7) * 8;
    const int vrow = tid >> 4, vcol = (tid & 15) * 8;
    const short* Kld = Kp + (size_t)krow * 64 + kcol;     // + kb*8192 + i*2048
    const short* Vld = Vp + (size_t)vrow * 2048 + vcol;   // + kb*128  + i*32768
    short* sKw = &sK[krow * LDP + kcol];
    short* sVw = &sVT[vrow * LDW + vcol];

    // Named prefetch registers — NOT arrays, NOT lambda-captured (R10 lesson:
    // addressable arrays spilled to scratch, WRITE_SIZE 21->270MB).
    uint4 kr0, kr1, kr2, kr3, vr0, vr1, vr2, vr3;
#define LOADKV(KB) do {                                                  \
        const short* _kp = Kld + (size_t)(KB) * 8192;                    \
        kr0 = *(const uint4*)(_kp);                                      \
        kr1 = *(const uint4*)(_kp + 32 * 64);                            \
        kr2 = *(const uint4*)(_kp + 64 * 64);                            \
        kr3 = *(const uint4*)(_kp + 96 * 64);                            \
        const short* _vp = Vld + (KB) * 128;                             \
        vr0 = *(const uint4*)(_vp);                                      \
        vr1 = *(const uint4*)(_vp + 16 * 2048);                          \
        vr2 = *(const uint4*)(_vp + 32 * 2048);                          \
        vr3 = *(const uint4*)(_vp + 48 * 2048);                          \
    } while (0)

    // Q fragment DIRECT to registers (wave reads only its own 16 q-rows).
    s16x8 aq[2];
#pragma unroll
    for (int ks = 0; ks < 2; ks++)
        aq[ks] = *(const s16x8*)(Qp + (size_t)(qt * 64 + w * 16 + l15) * 64 + ks * 32 + quad * 8);
    LOADKV(kb0);                     // prologue prefetch

    f32x4 o[4];
#pragma unroll
    for (int i = 0; i < 4; i++) o[i] = f32x4{0.f, 0.f, 0.f, 0.f};
    float lrun = 0.f;                // per-lane partial sum (quad-reduced at end)
    const int q_idx = qt * 64 + w * 16 + l15;

    for (int kb = kb0; kb <= kb1; kb++) {
        __syncthreads();             // prior iter's sK/sVT/sQP readers done
        // drain prefetched regs -> LDS (loads were issued one compute-phase ago)
        *(uint4*)(sKw)            = kr0;
        *(uint4*)(sKw + 32 * LDP) = kr1;
        *(uint4*)(sKw + 64 * LDP) = kr2;
        *(uint4*)(sKw + 96 * LDP) = kr3;
        *(uint4*)(sVw)            = vr0;
        *(uint4*)(sVw + 16 * LDW) = vr1;
        *(uint4*)(sVw + 32 * LDW) = vr2;
        *(uint4*)(sVw + 48 * LDW) = vr3;
        __syncthreads();
        if (kb < kb1) LOADKV(kb + 1);   // issue next tile; lands during compute below

        // S^T: 128 keys x 16 queries per wave. A = K rows (keys), B = Q^T.
        f32x4 sa[8];
#pragma unroll
        for (int i = 0; i < 8; i++) sa[i] = f32x4{0.f, 0.f, 0.f, 0.f};
        __builtin_amdgcn_s_setprio(1);
#pragma unroll
        for (int ks = 0; ks < 2; ks++) {
#pragma unroll
            for (int ct = 0; ct < 8; ct++) {
                s16x8 kf = *(const s16x8*)&sK[(ct * 16 + l15) * LDP + ks * 32 + quad * 8];
                sa[ct] = MFMA16(kf, aq[ks], sa[ct]);
            }
        }
        __builtin_amdgcn_s_setprio(0);

        float ps[8][4];
#pragma unroll
        for (int ct = 0; ct < 8; ct++)
#pragma unroll
            for (int r = 0; r < 4; r++) ps[ct][r] = sa[ct][r];

        if (kb == kbDiag) {          // uniform branch: only the diagonal block masks
#pragma unroll
            for (int ct = 0; ct < 8; ct++) {
                int kbase = kb * 128 + ct * 16 + quad * 4;
#pragma unroll
                for (int r = 0; r < 4; r++)
                    if ((kbase + r) > q_idx) ps[ct][r] = -INFINITY;
            }
        }

        // P = exp2(s) (no max subtraction), accumulate per-lane l
        float cm[8];
#pragma unroll
        for (int ct = 0; ct < 8; ct++) {
#pragma unroll
            for (int r = 0; r < 4; r++) ps[ct][r] = __builtin_amdgcn_exp2f(ps[ct][r]);
            cm[ct] = (ps[ct][0] + ps[ct][1]) + (ps[ct][2] + ps[ct][3]);
        }
        lrun += ((cm[0] + cm[1]) + (cm[2] + cm[3])) + ((cm[4] + cm[5]) + (cm[6] + cm[7]));

        // P^T (C-layout) -> sQP rows = query (wave-private), 8x ds_write_b64
#pragma unroll
        for (int ct = 0; ct < 8; ct++) {
            unsigned lo = pack2t(ps[ct][0], ps[ct][1]);
            unsigned hi = pack2t(ps[ct][2], ps[ct][3]);
            *(uint2*)&sQP[(w * 16 + l15) * LDW + ct * 16 + quad * 4] = make_uint2(lo, hi);
        }
        // no barrier: rows are wave-private, same-wave DS ops in-order

        // O += P V  (A = P rows=query, k = 128 keys; B = V^T rows = d)
        __builtin_amdgcn_s_setprio(1);
#pragma unroll
        for (int ks2 = 0; ks2 < 4; ks2++) {
            s16x8 pa = *(const s16x8*)&sQP[(w * 16 + l15) * LDW + ks2 * 32 + quad * 8];
#pragma unroll
            for (int ct = 0; ct < 4; ct++) {
                s16x8 vb = *(const s16x8*)&sVT[(ct * 16 + l15) * LDW + ks2 * 32 + quad * 8];
                o[ct] = MFMA16(pa, vb, o[ct]);
            }
        }
        __builtin_amdgcn_s_setprio(0);
    }
#undef LOADKV

    // epilogue: UNNORMALIZED partial O (bf16) + l (fp32, per query)
    const size_t pbase = ((size_t)(bh * 80 + u)) * 4096;
#pragma unroll
    for (int r = 0; r < 4; r++) {
        int row = w * 16 + quad * 4 + r;
#pragma unroll
        for (int ct = 0; ct < 4; ct++)
            paO[pbase + row * 64 + ct * 16 + l15] = f2bf(o[ct][r]);
    }
    lrun += __shfl_xor(lrun, 16);
    lrun += __shfl_xor(lrun, 32);
    if (quad == 0)
        ml[(bh * 80 + u) * 64 + w * 16 + l15] = lrun;
}

// ---------------------------------------------------------------------------
// Kernel 3b: combine partials (no-max scheme: L = sum l_i, Y = sum O_i / L).
// ---------------------------------------------------------------------------
__global__ __launch_bounds__(256) void combine_kernel(
    const short* __restrict__ paO, const float* __restrict__ ml, short* __restrict__ Y) {
    const int qt = blockIdx.x, bh = blockIdx.y;
    const int b = bh >> 4, h = bh & 15;
    const int nch = (qt >> 3) + 1;
    int base;
    if (qt < 8) base = qt;
    else if (qt < 16) base = 8 + 2 * (qt - 8);
    else if (qt < 24) base = 24 + 3 * (qt - 16);
    else base = 48 + 4 * (qt - 24);

    const int row = threadIdx.x >> 2;
    const int cq = (threadIdx.x & 3) * 16;

    float L = 0.f;
    for (int i = 0; i < nch; i++)
        L += ml[(bh * 80 + base + i) * 64 + row];
    const float inv = 1.0f / L;

    float acc[16];
#pragma unroll
    for (int j = 0; j < 16; j++) acc[j] = 0.f;
    for (int i = 0; i < nch; i++) {
        const short* p = paO + ((size_t)(bh * 80 + base + i)) * 4096 + row * 64 + cq;
        uint4 v0 = ((const uint4*)p)[0];
        uint4 v1 = ((const uint4*)p)[1];
        unsigned vs[8] = {v0.x, v0.y, v0.z, v0.w, v1.x, v1.y, v1.z, v1.w};
#pragma unroll
        for (int j = 0; j < 8; j++) {
            acc[2 * j + 0] += bf2f((short)(vs[j] & 0xFFFFu));
            acc[2 * j + 1] += bf2f((short)(vs[j] >> 16));
        }
    }
    const int t = qt * 64 + row;
    short* yp = Y + ((size_t)(b * 2048 + t)) * 1024 + h * 64 + cq;
    unsigned ow[8];
#pragma unroll
    for (int j = 0; j < 8; j++) ow[j] = pack2(acc[2 * j] * inv, acc[2 * j + 1] * inv);
    ((uint4*)yp)[0] = make_uint4(ow[0], ow[1], ow[2], ow[3]);
    ((uint4*)yp)[1] = make_uint4(ow[4], ow[5], ow[6], ow[7]);
}

// ---------------------------------------------------------------------------
// Kernel 4: output projection, 64x128 tiles -> 512 blocks. R16: XCD-chunked
// swizzle — each XCD gets an 8x8 (bx,by) sub-grid: 8 B-panels (2MB) + 8
// A-panels (1MB) = 3MB < 4MB per-XCD L2. Wave w owns a 64x32 slab. fp32 out.
// ---------------------------------------------------------------------------
__global__ __launch_bounds__(256) void oproj_kernel(
    const short* __restrict__ Yb, const short* __restrict__ Wob, float* __restrict__ out) {
    __shared__ __align__(16) short sA[64 * 64];
    __shared__ __align__(16) short sB[128 * 64];
    const int tid = threadIdx.x;
    const int w = tid >> 6, lane = tid & 63, quad = lane >> 4, l15 = lane & 15;
    // XCD swizzle: wid 0..511; xcd = wid&7; i = wid>>3 (0..63)
    const int wid = blockIdx.x + blockIdx.y * 8;
    const int xcd = wid & 7, si = wid >> 3;
    const int m0 = (xcd * 8 + (si >> 3)) * 64;
    const int nb = (si & 7) * 128;

    f32x4 acc[4][2];
#pragma unroll
    for (int i = 0; i < 4; i++)
#pragma unroll
        for (int j = 0; j < 2; j++) acc[i][j] = f32x4{0.f, 0.f, 0.f, 0.f};

    for (int kb = 0; kb < 16; kb++) {
        const int k0 = kb * 64;
        if (kb) __syncthreads();
#pragma unroll
        for (int i = 0; i < 2; i++) {      // A: 64x64 shorts = 512 chunks
            int c = i * 256 + tid;
            int row = c >> 3, col8 = (c & 7) * 8;
            async_ld16(Yb + (size_t)(m0 + row) * 1024 + k0 + col8,
                       &sA[(i * 256 + w * 64) * 8]);
        }
#pragma unroll
        for (int i = 0; i < 4; i++) {      // B: 128x64 shorts = 1024 chunks
            int c = i * 256 + tid;
            int row = c >> 3, col8 = (c & 7) * 8;
            async_ld16(Wob + (size_t)(nb + row) * 1024 + k0 + col8,
                       &sB[(i * 256 + w * 64) * 8]);
        }
        __syncthreads();
#pragma unroll
        for (int ks = 0; ks < 2; ks++) {
            s16x8 av[4], bv[2];
#pragma unroll
            for (int at = 0; at < 4; at++)
                av[at] = *(const s16x8*)&sA[(at * 16 + l15) * 64 + ks * 32 + quad * 8];
#pragma unroll
            for (int bt = 0; bt < 2; bt++)
                bv[bt] = *(const s16x8*)&sB[(w * 32 + bt * 16 + l15) * 64 + ks * 32 + quad * 8];
#pragma unroll
            for (int at = 0; at < 4; at++)
#pragma unroll
                for (int bt = 0; bt < 2; bt++)
                    acc[at][bt] = MFMA16(av[at], bv[bt], acc[at][bt]);
        }
    }
#pragma unroll
    for (int at = 0; at < 4; at++)
#pragma unroll
        for (int r = 0; r < 4; r++) {
            int m = m0 + at * 16 + quad * 4 + r;
#pragma unroll
            for (int bt = 0; bt < 2; bt++) {
                int n = nb + w * 32 + bt * 16 + l15;
                out[(size_t)m * 1024 + n] = acc[at][bt][r];
            }
        }
}

extern "C" void kernel_launch(void* const* d_in, const int* in_sizes, int n_in,
                              void* d_out, int out_size, void* d_ws, size_t ws_size,
                              hipStream_t stream) {
    (void)in_sizes; (void)n_in; (void)out_size; (void)ws_size;
    const float* x  = (const float*)d_in[0];
    const float* Wq = (const float*)d_in[1];
    const float* Wk = (const float*)d_in[2];
    const float* Wv = (const float*)d_in[3];
    const float* Wo = (const float*)d_in[4];
    float* out = (float*)d_out;

    const size_t NE = (size_t)2 * 16 * 2048 * 64;   // 4M elems per tensor
    short* Q   = (short*)d_ws;
    short* K   = Q + NE;
    short* VT  = K + NE;          // [B,H,D,T]
    short* Y   = VT + NE;         // attn output [B,T,C] bf16
    short* xb  = Y;               // x bf16 ALIASES Y: consumed by qkv before combine writes Y
    short* wb  = Y + NE;          // [Wq|Wk|Wv|Wo] bf16, 4M elems
    short* paO = wb + NE;         // partial O: 32 bh x 80 units x 64x64 bf16 = 21 MB
    float* ml  = (float*)(paO + (size_t)32 * 80 * 4096);   // l: 32x80x64 fp32

    convert_kernel<<<4096, 256, 0, stream>>>(x, Wq, Wk, Wv, Wo, xb, wb);
    qkv_kernel<<<dim3(24, 32), 256, 0, stream>>>(xb, wb, Q, K, VT);
    rope_kernel<<<512, 256, 0, stream>>>(Q, K);
    attn_kernel<<<dim3(80, 32), 256, 0, stream>>>(Q, K, VT, paO, ml);
    combine_kernel<<<dim3(32, 32), 256, 0, stream>>>(paO, ml, Y);
    oproj_kernel<<<dim3(8, 64), 256, 0, stream>>>(Y, wb + 3 * 1048576, out);
}